// Round 13
// baseline (7319.051 us; speedup 1.0000x reference)
//
#include <hip/hip_runtime.h>
#include <math.h>

#define S_LEN  4096
#define DMODEL 1024
#define NHEAD  16
#define DHEAD  64
#define DFF    4096
#define NLAYER 4
#define VOCAB  50257
#define NCBP   400   // partials row stride (col-blocks of 256, padded)

typedef unsigned short ushort_t;
typedef __attribute__((ext_vector_type(8))) __bf16 bf16x8;
typedef __attribute__((ext_vector_type(4))) float f32x4;

static __device__ __forceinline__ ushort_t f2bf(float f) {
  union { float f; unsigned u; } x; x.f = f;
  unsigned r = x.u + 0x7fffu + ((x.u >> 16) & 1u);
  return (ushort_t)(r >> 16);
}
static __device__ __forceinline__ float bf2f(ushort_t h) {
  union { unsigned u; float f; } x; x.u = ((unsigned)h) << 16;
  return x.f;
}
// 2^x via v_exp_f32 (avoid __exp2f: collides with glibc math.h macros)
static __device__ __forceinline__ float exp2fast(float x) {
  return __builtin_amdgcn_exp2f(x);
}

#define GLOAD_LDS16(gp, lp) \
  __builtin_amdgcn_global_load_lds((const __attribute__((address_space(1))) void*)(gp), \
                                   (__attribute__((address_space(3))) void*)(lp), 16, 0, 0)

// q pre-scale: 1/sqrt(64) * log2(e)  (softmax runs in exp2 domain)
#define QSCALE 0.18033688011112042f

// ---------------------------------------------------------------------------
// embedding + sinusoidal positional encoding, fused bf16 split (hi only)
// ---------------------------------------------------------------------------
__global__ __launch_bounds__(256) void embed_kernel(
    const int* __restrict__ tokens, const float* __restrict__ emb,
    float* __restrict__ x, ushort_t* __restrict__ xh)
{
  int s = blockIdx.x;
  int tok = tokens[s];
  int d0 = threadIdx.x * 4;
  const double lf = 0.01798894603901598653; // log(10000)/512
  float4 ev = *(const float4*)(emb + (size_t)tok * DMODEL + d0);
  float o[4]; float evr[4] = {ev.x, ev.y, ev.z, ev.w};
  #pragma unroll
  for (int j = 0; j < 4; ++j) {
    int d = d0 + j;
    int i = (d < 512) ? d : d - 512;
    double ang = (double)s * exp(-lf * (double)i);
    float pe = (d < 512) ? (float)sin(ang) : (float)cos(ang);
    o[j] = evr[j] + pe;
  }
  *(float4*)(x + (size_t)s * DMODEL + d0) = make_float4(o[0], o[1], o[2], o[3]);
  ushort_t hv[4];
  #pragma unroll
  for (int j = 0; j < 4; ++j) hv[j] = f2bf(o[j]);
  *(ushort4*)(xh + (size_t)s * DMODEL + d0) = make_ushort4(hv[0], hv[1], hv[2], hv[3]);
}

// ---------------------------------------------------------------------------
// transpose + split: in f32 [K][N] (row stride in_rstride) -> out bf16 hi/lo
// [N][Kout] K-contiguous. Two-level z batching: z1 = z % zdiv, z2 = z / zdiv.
// ---------------------------------------------------------------------------
__global__ __launch_bounds__(256)
void transpose_split(const float* __restrict__ in, ushort_t* __restrict__ oh,
                     ushort_t* __restrict__ ol,
                     long in_zstr, long out_zoff, long in_z2str, long out_z2off,
                     int zdiv, int in_rstride, int Kout, int Nvalid)
{
  __shared__ float tile[64][65];
  int z1 = blockIdx.z % zdiv, z2 = blockIdx.z / zdiv;
  long ioff = (long)z1 * in_zstr + (long)z2 * in_z2str;
  long ooff = (long)z1 * out_zoff + (long)z2 * out_z2off;
  const float* inz = in + ioff;
  ushort_t* ohz = oh + ooff;
  ushort_t* olz = ol + ooff;
  int k0 = blockIdx.x * 64, n0 = blockIdx.y * 64;
  int t = threadIdx.x;
  #pragma unroll
  for (int i = 0; i < 4; ++i) {
    int idx = t + i * 256;            // 0..1023
    int kk = idx >> 4, c4 = idx & 15;
    #pragma unroll
    for (int j = 0; j < 4; ++j) {
      int n = n0 + c4 * 4 + j;
      float v = (n < Nvalid) ? inz[(long)(k0 + kk) * in_rstride + n] : 0.f;
      tile[c4 * 4 + j][kk] = v;       // transposed into LDS
    }
  }
  __syncthreads();
  #pragma unroll
  for (int i = 0; i < 4; ++i) {
    int idx = t + i * 256;
    int nn = idx >> 4, k4 = idx & 15;
    ushort_t hv[4], lv[4];
    #pragma unroll
    for (int j = 0; j < 4; ++j) {
      float v = tile[nn][k4 * 4 + j];
      hv[j] = f2bf(v);
      lv[j] = f2bf(v - bf2f(hv[j]));
    }
    long ob = (long)(n0 + nn) * Kout + k0 + k4 * 4;
    *(ushort4*)(ohz + ob) = make_ushort4(hv[0], hv[1], hv[2], hv[3]);
    *(ushort4*)(olz + ob) = make_ushort4(lv[0], lv[1], lv[2], lv[3]);
  }
}

// hi-only variant (for the 1-product logits GEMM)
__global__ __launch_bounds__(256)
void transpose_h(const float* __restrict__ in, ushort_t* __restrict__ oh,
                 int in_rstride, int Kout, int Nvalid)
{
  __shared__ float tile[64][65];
  int k0 = blockIdx.x * 64, n0 = blockIdx.y * 64;
  int t = threadIdx.x;
  #pragma unroll
  for (int i = 0; i < 4; ++i) {
    int idx = t + i * 256;
    int kk = idx >> 4, c4 = idx & 15;
    #pragma unroll
    for (int j = 0; j < 4; ++j) {
      int n = n0 + c4 * 4 + j;
      float v = (n < Nvalid) ? in[(long)(k0 + kk) * in_rstride + n] : 0.f;
      tile[c4 * 4 + j][kk] = v;
    }
  }
  __syncthreads();
  #pragma unroll
  for (int i = 0; i < 4; ++i) {
    int idx = t + i * 256;
    int nn = idx >> 4, k4 = idx & 15;
    ushort_t hv[4];
    #pragma unroll
    for (int j = 0; j < 4; ++j) hv[j] = f2bf(tile[nn][k4 * 4 + j]);
    long ob = (long)(n0 + nn) * Kout + k0 + k4 * 4;
    *(ushort4*)(oh + ob) = make_ushort4(hv[0], hv[1], hv[2], hv[3]);
  }
}

// ---------------------------------------------------------------------------
// concat 3 bias vectors of length n into [3n], batched over layers (y)
// ---------------------------------------------------------------------------
__global__ __launch_bounds__(256)
void concat3_kernel(const float* __restrict__ a, const float* __restrict__ b,
                    const float* __restrict__ c, float* __restrict__ o,
                    int n, long lstrA, long lstrO)
{
  int i = blockIdx.x * 256 + threadIdx.x;
  long l = blockIdx.y;
  if (i < n) {
    o[l * lstrO + i]         = a[l * lstrA + i];
    o[l * lstrO + n + i]     = b[l * lstrA + i];
    o[l * lstrO + 2 * n + i] = c[l * lstrA + i];
  }
}

// ---------------------------------------------------------------------------
// 256x256-tile 8-wave GEMM, counted-vmcnt phase pipeline, 2-product split:
// C = Ah @ (Bh + Bl)^T. Streams Ah|Bh|Bl, double-buffered (96 KB LDS).
// EPI: 0 = raw f32 partial (split-K via blockIdx.z), 1 = bf16 hi C (+bias,
// RELU), 2 = QKV routing (q scaled hi/lo, k hi, v -> transposed [H][64][S]).
// ---------------------------------------------------------------------------
template<int EPI, bool RELU>
__global__ __launch_bounds__(512, 2)
void gemm8p(const ushort_t* __restrict__ Ah,
            const ushort_t* __restrict__ Bh, const ushort_t* __restrict__ Bl,
            const float* __restrict__ bias, float* __restrict__ C,
            ushort_t* __restrict__ O0, ushort_t* __restrict__ O1,
            ushort_t* __restrict__ O2, ushort_t* __restrict__ O4,
            int K, int ldk, long ldc, long czStride)
{
  constexpr int BUFSTR = 3 * 8192;              // Ah | Bh | Bl
  constexpr int OBH = 8192, OBL = 16384;
  __shared__ ushort_t lds[2 * BUFSTR];          // 96 KB

  const int t = threadIdx.x;
  const int l = t & 63;
  const int w = t >> 6;            // 0..7
  const int wr = w >> 2;           // 0..1  (row half)
  const int wc = w & 3;            // 0..3  (col quarter)
  const int lrow = l & 15;
  const int lk = (l >> 4) * 8;
  const int l8 = l * 8;
  const long m0 = (long)blockIdx.x * 256;
  const long n0 = (long)blockIdx.y * 256;
  const long kz = (long)blockIdx.z * K;

  const ushort_t *agp[2], *bgp[2], *blgp[2];
  int dst[2];
  #pragma unroll
  for (int i = 0; i < 2; ++i) {
    int s = i * 8 + w;                       // subtile 0..15
    dst[i] = s * 512 + l8;
    agp[i]  = Ah + (m0 + s * 16 + lrow) * (long)ldk + kz + lk;
    bgp[i]  = Bh + (n0 + s * 16 + lrow) * (long)ldk + kz + lk;
    blgp[i] = Bl + (n0 + s * 16 + lrow) * (long)ldk + kz + lk;
  }

  f32x4 acc[8][4];
  #pragma unroll
  for (int m = 0; m < 8; ++m)
    #pragma unroll
    for (int n = 0; n < 4; ++n) acc[m][n] = (f32x4)0.f;

  // prologue: stage tile 0, canonical per-tile order
  GLOAD_LDS16(agp[0],  &lds[dst[0]]);
  GLOAD_LDS16(agp[1],  &lds[dst[1]]);
  GLOAD_LDS16(bgp[0],  &lds[OBH + dst[0]]);
  GLOAD_LDS16(bgp[1],  &lds[OBH + dst[1]]);
  GLOAD_LDS16(blgp[0], &lds[OBL + dst[0]]);
  GLOAD_LDS16(blgp[1], &lds[OBL + dst[1]]);

  const int nk = K >> 5;
  int cur = 0;
  for (int kt = 0; kt < nk; ++kt) {
    const int knx = (kt + 1 < nk) ? (kt + 1) * 32 : 0;  // last iter: harmless reload
    ushort_t* cb = &lds[cur * BUFSTR];
    ushort_t* nb = &lds[(cur ^ 1) * BUFSTR];
    bf16x8 af[8], bhf[4], blf[4];

    // ---------- P0: needs Ah,Bh of tile kt ----------
    asm volatile("s_waitcnt vmcnt(2)" ::: "memory");
    __builtin_amdgcn_sched_barrier(0);
    __builtin_amdgcn_s_barrier();
    __builtin_amdgcn_sched_barrier(0);
    #pragma unroll
    for (int m = 0; m < 8; ++m)
      af[m] = *(const bf16x8*)&cb[(wr * 8 + m) * 512 + l8];
    #pragma unroll
    for (int n = 0; n < 4; ++n)
      bhf[n] = *(const bf16x8*)&cb[OBH + (wc * 4 + n) * 512 + l8];
    GLOAD_LDS16(agp[0] + knx, &nb[dst[0]]);
    GLOAD_LDS16(agp[1] + knx, &nb[dst[1]]);
    GLOAD_LDS16(bgp[0] + knx, &nb[OBH + dst[0]]);
    __builtin_amdgcn_s_setprio(1);
    #pragma unroll
    for (int m = 0; m < 8; ++m)
      #pragma unroll
      for (int n = 0; n < 4; ++n)
        acc[m][n] = __builtin_amdgcn_mfma_f32_16x16x32_bf16(af[m], bhf[n], acc[m][n], 0, 0, 0);
    __builtin_amdgcn_s_setprio(0);
    __builtin_amdgcn_sched_barrier(0);

    // ---------- P1: needs Bl of tile kt ----------
    asm volatile("s_waitcnt vmcnt(3)" ::: "memory");
    __builtin_amdgcn_sched_barrier(0);
    __builtin_amdgcn_s_barrier();
    __builtin_amdgcn_sched_barrier(0);
    #pragma unroll
    for (int n = 0; n < 4; ++n)
      blf[n] = *(const bf16x8*)&cb[OBL + (wc * 4 + n) * 512 + l8];
    GLOAD_LDS16(bgp[1] + knx,  &nb[OBH + dst[1]]);
    GLOAD_LDS16(blgp[0] + knx, &nb[OBL + dst[0]]);
    GLOAD_LDS16(blgp[1] + knx, &nb[OBL + dst[1]]);
    __builtin_amdgcn_s_setprio(1);
    #pragma unroll
    for (int m = 0; m < 8; ++m)
      #pragma unroll
      for (int n = 0; n < 4; ++n)
        acc[m][n] = __builtin_amdgcn_mfma_f32_16x16x32_bf16(af[m], blf[n], acc[m][n], 0, 0, 0);
    __builtin_amdgcn_s_setprio(0);
    __builtin_amdgcn_sched_barrier(0);
    cur ^= 1;
  }
  asm volatile("s_waitcnt vmcnt(0)" ::: "memory");

  // ---------------- epilogue (row-major store order for line combining) ----
  if constexpr (EPI == 2) {
    #pragma unroll
    for (int n = 0; n < 4; ++n) {
      long col = n0 + wc * 64 + n * 16 + lrow;
      float bv = bias[col];
      #pragma unroll
      for (int m = 0; m < 8; ++m) {
        #pragma unroll
        for (int r = 0; r < 4; ++r) {
          long row = m0 + wr * 128 + m * 16 + (l >> 4) * 4 + r;
          float v = acc[m][n][r] + bv;
          int c = (int)col;
          if (c < 1024) {
            int hh = c >> 6, e = c & 63;
            float qv = v * QSCALE;            // fold 1/sqrt(DH)*log2e
            ushort_t hi = f2bf(qv);
            size_t a = ((size_t)hh * S_LEN + row) * 64 + e;
            O0[a] = hi; O1[a] = f2bf(qv - bf2f(hi));
          } else if (c < 2048) {
            int cc = c - 1024;
            int hh = cc >> 6, e = cc & 63;
            size_t a = ((size_t)hh * S_LEN + row) * 64 + e;
            O2[a] = f2bf(v);
          } else {
            // V: write transposed directly -> vt[h][e][row]
            int cc = c - 2048;
            int hh = cc >> 6, e = cc & 63;
            size_t a = ((size_t)hh * DHEAD + e) * S_LEN + row;
            O4[a] = f2bf(v);
          }
        }
      }
    }
  } else if constexpr (EPI == 1) {
    long col4[4]; float bv4[4];
    #pragma unroll
    for (int n = 0; n < 4; ++n) {
      col4[n] = n0 + wc * 64 + n * 16 + lrow;
      bv4[n] = bias[col4[n]];
    }
    #pragma unroll
    for (int m = 0; m < 8; ++m) {
      #pragma unroll
      for (int r = 0; r < 4; ++r) {
        long row = m0 + wr * 128 + m * 16 + (l >> 4) * 4 + r;
        ushort_t* crow = O0 + row * ldc;
        #pragma unroll
        for (int n = 0; n < 4; ++n) {
          float v = acc[m][n][r] + bv4[n];
          if (RELU) v = fmaxf(v, 0.f);
          crow[col4[n]] = f2bf(v);
        }
      }
    }
  } else {  // EPI == 0: raw f32 partial (split-K), no bias
    float* Cz = C + (long)blockIdx.z * czStride;
    long col4[4];
    #pragma unroll
    for (int n = 0; n < 4; ++n) col4[n] = n0 + wc * 64 + n * 16 + lrow;
    #pragma unroll
    for (int m = 0; m < 8; ++m) {
      #pragma unroll
      for (int r = 0; r < 4; ++r) {
        long row = m0 + wr * 128 + m * 16 + (l >> 4) * 4 + r;
        float* crow = Cz + row * ldc;
        #pragma unroll
        for (int n = 0; n < 4; ++n) crow[col4[n]] = acc[m][n][r];
      }
    }
  }
}

// ---------------------------------------------------------------------------
// 1-product 256x256 GEMM (logits): C = exp(Ah@Bh^T + bias), per-row partials.
// 2-buffer depth-1 pipeline, 64 KB LDS -> 2 blocks/CU (cross-block latency
// hiding, same mechanism as attn_mfma). One barrier per K-step.
// ---------------------------------------------------------------------------
template<bool BOUND>
__global__ __launch_bounds__(512, 4)
void gemm1p(const ushort_t* __restrict__ Ah, const ushort_t* __restrict__ Bh,
            const float* __restrict__ bias, float* __restrict__ C,
            int K, int ldk, long ldc, int Nlimit,
            float* __restrict__ Ppart, int cbbase)
{
  constexpr int OB = 8192;
  constexpr int BUFSTR = 16384;        // shorts per buffer (A 16KB | B 16KB)
  __shared__ ushort_t lds[2 * BUFSTR]; // 64 KB -> 2 blocks/CU
  __shared__ float psum[1024];

  const int t = threadIdx.x;
  const int l = t & 63;
  const int w = t >> 6;
  const int wr = w >> 2;
  const int wc = w & 3;
  const int lrow = l & 15;
  const int lk = (l >> 4) * 8;
  const int l8 = l * 8;
  const long m0 = (long)blockIdx.x * 256;
  const long n0 = (long)blockIdx.y * 256;

  const ushort_t *agp[2], *bgp[2];
  int dst[2];
  #pragma unroll
  for (int i = 0; i < 2; ++i) {
    int s = i * 8 + w;
    dst[i] = s * 512 + l8;
    agp[i] = Ah + (m0 + s * 16 + lrow) * (long)ldk + lk;
    bgp[i] = Bh + (n0 + s * 16 + lrow) * (long)ldk + lk;
  }

  f32x4 acc[8][4];
  #pragma unroll
  for (int m = 0; m < 8; ++m)
    #pragma unroll
    for (int n = 0; n < 4; ++n) acc[m][n] = (f32x4)0.f;

  // prologue: tile 0 -> buf0 (4 loads outstanding)
  GLOAD_LDS16(agp[0], &lds[dst[0]]);
  GLOAD_LDS16(agp[1], &lds[dst[1]]);
  GLOAD_LDS16(bgp[0], &lds[OB + dst[0]]);
  GLOAD_LDS16(bgp[1], &lds[OB + dst[1]]);

  const int nk = K >> 5;
  int cur = 0;
  for (int kt = 0; kt < nk; ++kt) {
    ushort_t* cb = &lds[cur * BUFSTR];
    ushort_t* nb = &lds[(cur ^ 1) * BUFSTR];
    bf16x8 af[8], bhf[4];

    asm volatile("s_waitcnt vmcnt(0)" ::: "memory");   // tile kt landed
    __builtin_amdgcn_sched_barrier(0);
    __builtin_amdgcn_s_barrier();
    __builtin_amdgcn_sched_barrier(0);
    #pragma unroll
    for (int m = 0; m < 8; ++m)
      af[m] = *(const bf16x8*)&cb[(wr * 8 + m) * 512 + l8];
    #pragma unroll
    for (int n = 0; n < 4; ++n)
      bhf[n] = *(const bf16x8*)&cb[OB + (wc * 4 + n) * 512 + l8];
    const int knx = (kt + 1 < nk) ? (kt + 1) * 32 : 0;  // tail: harmless refill
    GLOAD_LDS16(agp[0] + knx, &nb[dst[0]]);
    GLOAD_LDS16(agp[1] + knx, &nb[dst[1]]);
    GLOAD_LDS16(bgp[0] + knx, &nb[OB + dst[0]]);
    GLOAD_LDS16(bgp[1] + knx, &nb[OB + dst[1]]);
    __builtin_amdgcn_s_setprio(1);
    #pragma unroll
    for (int m = 0; m < 8; ++m)
      #pragma unroll
      for (int n = 0; n < 4; ++n)
        acc[m][n] = __builtin_amdgcn_mfma_f32_16x16x32_bf16(af[m], bhf[n], acc[m][n], 0, 0, 0);
    __builtin_amdgcn_s_setprio(0);
    __builtin_amdgcn_sched_barrier(0);
    cur ^= 1;
  }
  asm volatile("s_waitcnt vmcnt(0)" ::: "memory");

  // epilogue: exp(logit), row-major store order + deterministic partial sums
  float smr[8][4];
  #pragma unroll
  for (int m = 0; m < 8; ++m)
    #pragma unroll
    for (int r = 0; r < 4; ++r) smr[m][r] = 0.f;
  long col4[4]; float bv4[4]; bool cok4[4];
  #pragma unroll
  for (int n = 0; n < 4; ++n) {
    col4[n] = n0 + wc * 64 + n * 16 + lrow;
    cok4[n] = (!BOUND) || (col4[n] < (long)Nlimit);
    bv4[n] = cok4[n] ? bias[col4[n]] : 0.f;
  }
  #pragma unroll
  for (int m = 0; m < 8; ++m) {
    #pragma unroll
    for (int r = 0; r < 4; ++r) {
      long row = m0 + wr * 128 + m * 16 + (l >> 4) * 4 + r;
      float* crow = C + row * ldc;
      #pragma unroll
      for (int n = 0; n < 4; ++n) {
        float e = cok4[n] ? __expf(acc[m][n][r] + bv4[n]) : 0.f;
        if (cok4[n]) crow[col4[n]] = e;
        smr[m][r] += e;
      }
    }
  }
  #pragma unroll
  for (int m = 0; m < 8; ++m) {
    #pragma unroll
    for (int r = 0; r < 4; ++r) {
      float s = smr[m][r];
      s += __shfl_xor(s, 1);
      s += __shfl_xor(s, 2);
      s += __shfl_xor(s, 4);
      s += __shfl_xor(s, 8);
      if (lrow == 0)
        psum[wc * 256 + wr * 128 + m * 16 + (l >> 4) * 4 + r] = s;
    }
  }
  __syncthreads();
  if (t < 256) {
    float s = psum[t] + psum[256 + t] + psum[512 + t] + psum[768 + t];
    Ppart[(m0 + t) * NCBP + cbbase + blockIdx.y] = s;
  }
}

// ---------------------------------------------------------------------------
// MFMA flash attention v3. qh/ql: [H][S][64] bf16 (pre-scaled by QSCALE),
// kh: [H][S][64] bf16, vt: [H][64][S] bf16. y: [S][1024] f32.
// 2-product QK^T; exp2-domain softmax; defer-rescale vote; K/V double-buffer
// with next-tile loads issued a full compute-phase early (1 barrier/tile).
// ---------------------------------------------------------------------------
__global__ __launch_bounds__(256)
void attn_mfma(const ushort_t* __restrict__ qh, const ushort_t* __restrict__ ql,
               const ushort_t* __restrict__ kh, const ushort_t* __restrict__ vt,
               float* __restrict__ y)
{
  __shared__ ushort_t lds[24576];  // buf0 K|V [8192], buf1 K|V [8192], P [4][2048]

  const int t = threadIdx.x, l = t & 63, w = t >> 6;
  const int lrow = l & 15, lhi = l >> 4;
  const int h = blockIdx.y;
  const int bw = blockIdx.x * 128 + w * 32;
  const size_t hS = (size_t)h * S_LEN * DHEAD;
  const size_t hV = (size_t)h * DHEAD * S_LEN;
  const int pb = 16384 + w * 2048;

  bf16x8 qhf[2][2], qlf[2][2];
  #pragma unroll
  for (int m = 0; m < 2; ++m)
    #pragma unroll
    for (int ks = 0; ks < 2; ++ks) {
      size_t a = hS + (size_t)(bw + m * 16 + lrow) * 64 + ks * 32 + lhi * 8;
      qhf[m][ks] = *(const bf16x8*)(qh + a);
      qlf[m][ks] = *(const bf16x8*)(ql + a);
    }

  f32x4 acc[2][4];
  #pragma unroll
  for (int m = 0; m < 2; ++m)
    #pragma unroll
    for (int n = 0; n < 4; ++n) acc[m][n] = (f32x4)0.f;
  float mrow[8], lsum[8];
  #pragma unroll
  for (int i = 0; i < 8; ++i) { mrow[i] = -1e30f; lsum[i] = 0.f; }

  // prologue: stage tile 0 into buf 0
  #pragma unroll
  for (int i = 0; i < 2; ++i) {
    int s = i * 4 + w;
    size_t krow = (size_t)((s >> 1) * 16 + lrow);
    int koff = (s & 1) * 32 + lhi * 8;
    GLOAD_LDS16(kh + hS + krow * 64 + koff, &lds[s * 512 + l * 8]);
    int toff = (s & 1) * 32 + lhi * 8;
    GLOAD_LDS16(vt + hV + krow * S_LEN + toff, &lds[4096 + s * 512 + l * 8]);
  }

  int cur = 0;
  for (int kt = 0; kt < S_LEN; kt += 64) {
    asm volatile("s_waitcnt vmcnt(0)" ::: "memory");
    __builtin_amdgcn_sched_barrier(0);
    __builtin_amdgcn_s_barrier();
    __builtin_amdgcn_sched_barrier(0);
    ushort_t* cb = &lds[cur * 8192];
    // issue next-tile loads into the other buffer (hidden under compute)
    if (kt + 64 < S_LEN) {
      ushort_t* nb = &lds[(cur ^ 1) * 8192];
      int kn = kt + 64;
      #pragma unroll
      for (int i = 0; i < 2; ++i) {
        int s = i * 4 + w;
        size_t krow = (size_t)(kn + (s >> 1) * 16 + lrow);
        int koff = (s & 1) * 32 + lhi * 8;
        GLOAD_LDS16(kh + hS + krow * 64 + koff, &nb[s * 512 + l * 8]);
        size_t erow = (size_t)((s >> 1) * 16 + lrow);
        int toff = kn + (s & 1) * 32 + lhi * 8;
        GLOAD_LDS16(vt + hV + erow * S_LEN + toff, &nb[4096 + s * 512 + l * 8]);
      }
    }

    // scores (exp2 domain), 2-product: (qh + ql) * kh
    f32x4 sacc[2][4];
    #pragma unroll
    for (int m = 0; m < 2; ++m)
      #pragma unroll
      for (int n = 0; n < 4; ++n) sacc[m][n] = (f32x4)0.f;
    #pragma unroll
    for (int ks = 0; ks < 2; ++ks) {
      bf16x8 bh_[4];
      #pragma unroll
      for (int n = 0; n < 4; ++n)
        bh_[n] = *(const bf16x8*)&cb[(n * 2 + ks) * 512 + l * 8];
      #pragma unroll
      for (int m = 0; m < 2; ++m)
        #pragma unroll
        for (int n = 0; n < 4; ++n) {
          sacc[m][n] = __builtin_amdgcn_mfma_f32_16x16x32_bf16(qhf[m][ks], bh_[n], sacc[m][n], 0, 0, 0);
          sacc[m][n] = __builtin_amdgcn_mfma_f32_16x16x32_bf16(qlf[m][ks], bh_[n], sacc[m][n], 0, 0, 0);
        }
    }

    // tile maxes + wave vote (defer rescale when no row's max grew)
    float tmv[2][4];
    bool up = false;
    #pragma unroll
    for (int m = 0; m < 2; ++m) {
      #pragma unroll
      for (int r = 0; r < 4; ++r) {
        float tm = fmaxf(fmaxf(sacc[m][0][r], sacc[m][1][r]),
                         fmaxf(sacc[m][2][r], sacc[m][3][r]));
        tm = fmaxf(tm, __shfl_xor(tm, 1));
        tm = fmaxf(tm, __shfl_xor(tm, 2));
        tm = fmaxf(tm, __shfl_xor(tm, 4));
        tm = fmaxf(tm, __shfl_xor(tm, 8));
        tmv[m][r] = tm;
        up = up || (tm > mrow[m * 4 + r]);
      }
    }
    if (__ballot(up) != 0ULL) {
      #pragma unroll
      for (int m = 0; m < 2; ++m) {
        #pragma unroll
        for (int r = 0; r < 4; ++r) {
          const int idx = m * 4 + r;
          float mn = fmaxf(mrow[idx], tmv[m][r]);
          float al = exp2fast(mrow[idx] - mn);
          mrow[idx] = mn;
          lsum[idx] *= al;
          #pragma unroll
          for (int n = 0; n < 4; ++n) acc[m][n][r] *= al;
        }
      }
    }
    #pragma unroll
    for (int m = 0; m < 2; ++m) {
      #pragma unroll
      for (int r = 0; r < 4; ++r) {
        const int idx = m * 4 + r;
        float rs = 0.f;
        #pragma unroll
        for (int n = 0; n < 4; ++n) {
          float p = exp2fast(sacc[m][n][r] - mrow[idx]);
          rs += p;
          int pa = pb + ((m * 2 + (n >> 1)) << 9) + (((n & 1) * 2 + (lrow >> 3)) << 7)
                   + ((lhi * 4 + r) << 3) + (l & 7);
          pa ^= (lrow >> 3) << 3;
          lds[pa] = f2bf(p);
        }
        rs += __shfl_xor(rs, 1);
        rs += __shfl_xor(rs, 2);
        rs += __shfl_xor(rs, 4);
        rs += __shfl_xor(rs, 8);
        lsum[idx] += rs;
      }
    }

    // O += P V
    #pragma unroll
    for (int ks = 0; ks < 2; ++ks) {
      bf16x8 pa_[2];
      #pragma unroll
      for (int m = 0; m < 2; ++m) {
        int ra = pb + ((m * 2 + ks) << 9) + (l << 3);
        ra ^= ((l >> 4) & 1) << 3;
        pa_[m] = *(const bf16x8*)&lds[ra];
      }
      #pragma unroll
      for (int n = 0; n < 4; ++n) {
        bf16x8 vf = *(const bf16x8*)&cb[4096 + (n * 2 + ks) * 512 + l * 8];
        #pragma unroll
        for (int m = 0; m < 2; ++m)
          acc[m][n] = __builtin_amdgcn_mfma_f32_16x16x32_bf16(pa_[m], vf, acc[m][n], 0, 0, 0);
      }
    }
    cur ^= 1;
  }

  #pragma unroll
  for (int m = 0; m < 2; ++m) {
    #pragma unroll
    for (int r = 0; r < 4; ++r) {
      float inv = 1.0f / lsum[m * 4 + r];
      int row = bw + m * 16 + lhi * 4 + r;
      #pragma unroll
      for (int n = 0; n < 4; ++n)
        y[(size_t)row * DMODEL + h * 64 + n * 16 + lrow] = acc[m][n][r] * inv;
    }
  }
}

// ---------------------------------------------------------------------------
__device__ __forceinline__ float block_sum256(float v, float* sm)
{
  #pragma unroll
  for (int off = 32; off >= 1; off >>= 1) v += __shfl_xor(v, off);
  int w = threadIdx.x >> 6;
  if ((threadIdx.x & 63) == 0) sm[w] = v;
  __syncthreads();
  v = sm[0] + sm[1] + sm[2] + sm[3];
  __syncthreads();
  return v;
}

// x = layernorm(x + y) * g + b, fused bf16 (hi only) split of the result
__global__ __launch_bounds__(256)
void resid_ln_kernel(float* __restrict__ x, const float* __restrict__ y,
                     const float* __restrict__ g, const float* __restrict__ b,
                     ushort_t* __restrict__ xh)
{
  __shared__ float sm[4];
  int row = blockIdx.x, t = threadIdx.x;
  float4 xv = *(const float4*)(x + (size_t)row * DMODEL + t * 4);
  float4 yv = *(const float4*)(y + (size_t)row * DMODEL + t * 4);
  float a0 = xv.x + yv.x, a1 = xv.y + yv.y, a2 = xv.z + yv.z, a3 = xv.w + yv.w;
  float s = block_sum256(a0 + a1 + a2 + a3, sm);
  float mean = s * (1.0f / DMODEL);
  float d0 = a0 - mean, d1 = a1 - mean, d2 = a2 - mean, d3 = a3 - mean;
  float vs = block_sum256(d0*d0 + d1*d1 + d2*d2 + d3*d3, sm);
  float inv = rsqrtf(vs * (1.0f / DMODEL) + 1e-5f);
  float4 gv = *(const float4*)(g + t * 4);
  float4 bv = *(const float4*)(b + t * 4);
  float o[4];
  o[0] = d0 * inv * gv.x + bv.x;
  o[1] = d1 * inv * gv.y + bv.y;
  o[2] = d2 * inv * gv.z + bv.z;
  o[3] = d3 * inv * gv.w + bv.w;
  *(float4*)(x + (size_t)row * DMODEL + t * 4) = make_float4(o[0], o[1], o[2], o[3]);
  ushort_t hv[4];
  #pragma unroll
  for (int j = 0; j < 4; ++j) hv[j] = f2bf(o[j]);
  *(ushort4*)(xh + (size_t)row * DMODEL + t * 4) = make_ushort4(hv[0], hv[1], hv[2], hv[3]);
}

// ---------------------------------------------------------------------------
// x = layernorm(x + sum_{z<4} parts[z] + bias) * g + b, fused bf16 hi split.
// ---------------------------------------------------------------------------
__global__ __launch_bounds__(256)
void resid_ln_red(float* __restrict__ x, const float* __restrict__ parts,
                  long pstride, const float* __restrict__ bias,
                  const float* __restrict__ g, const float* __restrict__ b,
                  ushort_t* __restrict__ xh)
{
  __shared__ float sm[4];
  int row = blockIdx.x, t = threadIdx.x;
  size_t base = (size_t)row * DMODEL + t * 4;
  float4 xv = *(const float4*)(x + base);
  float4 bb = *(const float4*)(bias + t * 4);
  float a0 = xv.x + bb.x, a1 = xv.y + bb.y, a2 = xv.z + bb.z, a3 = xv.w + bb.w;
  #pragma unroll
  for (int z = 0; z < 4; ++z) {
    float4 pv = *(const float4*)(parts + (size_t)z * pstride + base);
    a0 += pv.x; a1 += pv.y; a2 += pv.z; a3 += pv.w;
  }
  float s = block_sum256(a0 + a1 + a2 + a3, sm);
  float mean = s * (1.0f / DMODEL);
  float d0 = a0 - mean, d1 = a1 - mean, d2 = a2 - mean, d3 = a3 - mean;
  float vs = block_sum256(d0*d0 + d1*d1 + d2*d2 + d3*d3, sm);
  float inv = rsqrtf(vs * (1.0f / DMODEL) + 1e-5f);
  float4 gv = *(const float4*)(g + t * 4);
  float4 bv = *(const float4*)(b + t * 4);
  float o[4];
  o[0] = d0 * inv * gv.x + bv.x;
  o[1] = d1 * inv * gv.y + bv.y;
  o[2] = d2 * inv * gv.z + bv.z;
  o[3] = d3 * inv * gv.w + bv.w;
  *(float4*)(x + base) = make_float4(o[0], o[1], o[2], o[3]);
  ushort_t hv[4];
  #pragma unroll
  for (int j = 0; j < 4; ++j) hv[j] = f2bf(o[j]);
  *(ushort4*)(xh + base) = make_ushort4(hv[0], hv[1], hv[2], hv[3]);
}

// ---------------------------------------------------------------------------
// final scale: out[row] *= 1/sum(row); sum from deterministic partials
// ---------------------------------------------------------------------------
__global__ __launch_bounds__(256)
void scale_softmax(float* __restrict__ out, const float* __restrict__ partials,
                   int ncb)
{
  __shared__ float sm[4];
  int row = blockIdx.x, t = threadIdx.x;
  float s = 0.f;
  for (int cb = t; cb < ncb; cb += 256) s += partials[(size_t)row * NCBP + cb];
  s = block_sum256(s, sm);
  float inv = 1.0f / s;
  float* p = out + (size_t)row * VOCAB;
  int head = (int)((((uintptr_t)16 - ((uintptr_t)p & 15)) & 15) >> 2);
  if (t < head) p[t] *= inv;
  int nvec = (VOCAB - head) >> 2;
  float4* pv = (float4*)(p + head);
  for (int i = t; i < nvec; i += 256) {
    float4 v = pv[i];
    v.x *= inv; v.y *= inv; v.z *= inv; v.w *= inv;
    pv[i] = v;
  }
  int done = head + nvec * 4;
  if (t < VOCAB - done) p[done + t] *= inv;
}

// ---------------------------------------------------------------------------
extern "C" void kernel_launch(void* const* d_in, const int* in_sizes, int n_in,
                              void* d_out, int out_size, void* d_ws, size_t ws_size,
                              hipStream_t stream)
{
  const int*   tokens = (const int*)  d_in[0];
  const float* emb    = (const float*)d_in[1];
  const float* Wq     = (const float*)d_in[2];
  const float* bq     = (const float*)d_in[3];
  const float* Wk     = (const float*)d_in[4];
  const float* bk     = (const float*)d_in[5];
  const float* Wv     = (const float*)d_in[6];
  const float* bv     = (const float*)d_in[7];
  const float* ln1g   = (const float*)d_in[8];
  const float* ln1b   = (const float*)d_in[9];
  const float* W1     = (const float*)d_in[10];
  const float* b1     = (const float*)d_in[11];
  const float* W2     = (const float*)d_in[12];
  const float* b2     = (const float*)d_in[13];
  const float* ln2g   = (const float*)d_in[14];
  const float* ln2b   = (const float*)d_in[15];
  const float* Wout   = (const float*)d_in[16];
  const float* bout   = (const float*)d_in[17];

  // workspace: xh 0-8 MB; strip path stripH 8-16; partials 24-30.55;
  // big path (ws >= 137 MB): WoutT at 32 MB (50304x1024 bf16 = 103 MB)
  char* wsb = (char*)d_ws;
  ushort_t* xh     = (ushort_t*)(wsb);
  ushort_t* stripH = (ushort_t*)(wsb + ((size_t)8  << 20));
  float*    partials = (float*)(wsb + ((size_t)24 << 20)); // [4096][NCBP] f32
  ushort_t* woutT  = (ushort_t*)(wsb + ((size_t)32 << 20));
  const bool bigws = ws_size >= ((size_t)137 << 20);

  // scratch in d_out (823 MB; all dead before the logits GEMM writes it)
  char* ob = (char*)d_out;
  float*    x     = (float*)(ob);                          // [S][D] f32 16MB
  float*    yb    = (float*)(ob + ((size_t)16  << 20));    // [S][D] f32 16MB
  ushort_t* qh    = (ushort_t*)(ob + ((size_t)32  << 20)); // [H][S][64] 8MB
  ushort_t* ql    = (ushort_t*)(ob + ((size_t)40  << 20));
  ushort_t* kh    = (ushort_t*)(ob + ((size_t)48  << 20));
  ushort_t* vt    = (ushort_t*)(ob + ((size_t)56  << 20)); // [H][64][S] 8MB
  ushort_t* h1h   = (ushort_t*)(ob + ((size_t)64  << 20)); // [S][DFF] bf16 32MB
  float*    fparts= (float*)(ob + ((size_t)96  << 20));    // [4][S][D] f32 64MB
  ushort_t* wqkvhA= (ushort_t*)(ob + ((size_t)160 << 20)); // [L][3072][1024] 24MB
  ushort_t* wqkvlA= (ushort_t*)(ob + ((size_t)184 << 20));
  ushort_t* w1hA  = (ushort_t*)(ob + ((size_t)208 << 20)); // [L][4096][1024] 32MB
  ushort_t* w1lA  = (ushort_t*)(ob + ((size_t)240 << 20));
  ushort_t* w2hA  = (ushort_t*)(ob + ((size_t)272 << 20)); // [L][1024][4096] 32MB
  ushort_t* w2lA  = (ushort_t*)(ob + ((size_t)304 << 20));
  float*    bqkvA = (float*)(ob + ((size_t)336 << 20));    // [L][3072] f32
  float*    outf  = (float*)d_out;

  const long WQKV_L = 3072L * 1024;   // shorts per layer
  const long WFF_L  = 4096L * 1024;

  embed_kernel<<<S_LEN, 256, 0, stream>>>(tokens, emb, x, xh);

  // ---- hoisted weight prep (activation-independent) ----
  transpose_split<<<dim3(16, 1, 64), 256, 0, stream>>>(
      Wq, wqkvhA, wqkvlA,
      (long)DMODEL * DHEAD, (long)DHEAD * DMODEL,
      (long)NHEAD * DMODEL * DHEAD, WQKV_L,
      16, DHEAD, DMODEL, DHEAD);
  transpose_split<<<dim3(16, 1, 64), 256, 0, stream>>>(
      Wk, wqkvhA + 1024 * 1024, wqkvlA + 1024 * 1024,
      (long)DMODEL * DHEAD, (long)DHEAD * DMODEL,
      (long)NHEAD * DMODEL * DHEAD, WQKV_L,
      16, DHEAD, DMODEL, DHEAD);
  transpose_split<<<dim3(16, 1, 64), 256, 0, stream>>>(
      Wv, wqkvhA + 2048 * 1024, wqkvlA + 2048 * 1024,
      (long)DMODEL * DHEAD, (long)DHEAD * DMODEL,
      (long)NHEAD * DMODEL * DHEAD, WQKV_L,
      16, DHEAD, DMODEL, DHEAD);
  transpose_split<<<dim3(16, 64, 4), 256, 0, stream>>>(
      W1, w1hA, w1lA, 0, 0,
      (long)DMODEL * DFF, WFF_L, 1, DFF, DMODEL, DFF);
  transpose_split<<<dim3(64, 16, 4), 256, 0, stream>>>(
      W2, w2hA, w2lA, 0, 0,
      (long)DFF * DMODEL, WFF_L, 1, DMODEL, DFF, DMODEL);
  concat3_kernel<<<dim3(4, NLAYER), 256, 0, stream>>>(
      bq, bk, bv, bqkvA, 1024, 1024, 3072);

  for (int l = 0; l < NLAYER; ++l) {
    const ushort_t* wqh = wqkvhA + (long)l * WQKV_L;
    const ushort_t* wql = wqkvlA + (long)l * WQKV_L;
    const ushort_t* w1h = w1hA + (long)l * WFF_L;
    const ushort_t* w1l = w1lA + (long)l * WFF_L;
    const ushort_t* w2h = w2hA + (long)l * WFF_L;
    const ushort_t* w2l = w2lA + (long)l * WFF_L;

    // fused QKV projection: 2-prod, grid 16x12; V written transposed
    gemm8p<2, false><<<dim3(16, 12), 512, 0, stream>>>(
        xh, wqh, wql, bqkvA + (long)l * 3072, nullptr,
        qh, ql, kh, vt, 1024, 1024, 0, 0);

    attn_mfma<<<dim3(32, 16), 256, 0, stream>>>(qh, ql, kh, vt, yb);

    resid_ln_kernel<<<S_LEN, 256, 0, stream>>>(x, yb,
        ln1g + (size_t)l * DMODEL, ln1b + (size_t)l * DMODEL, xh);

    // FFN1: 2-prod, grid 16x16, bf16-hi output
    gemm8p<1, true><<<dim3(16, 16), 512, 0, stream>>>(
        xh, w1h, w1l, b1 + (long)l * DFF, nullptr,
        h1h, nullptr, nullptr, nullptr, 1024, 1024, 4096, 0);
    // FFN2: 2-prod split-K x4 (grid 16x4x4), f32 partials
    gemm8p<0, false><<<dim3(16, 4, 4), 512, 0, stream>>>(
        h1h, w2h, w2l, nullptr, fparts,
        nullptr, nullptr, nullptr, nullptr,
        1024, 4096, 1024, (long)S_LEN * DMODEL);
    resid_ln_red<<<S_LEN, 256, 0, stream>>>(x, fparts, (long)S_LEN * DMODEL,
        b2 + (long)l * DMODEL,
        ln2g + (size_t)l * DMODEL, ln2b + (size_t)l * DMODEL, xh);
  }

  if (bigws) {
    // single-shot logits: whole Wout^T (hi) staged in ws, one GEMM
    transpose_h<<<dim3(16, 786, 1), 256, 0, stream>>>(
        Wout, woutT, VOCAB, DMODEL, VOCAB);
    gemm1p<true><<<dim3(16, 197), 512, 0, stream>>>(
        xh, woutT, bout, outf, 1024, 1024, VOCAB, VOCAB, partials, 0);
  } else {
    // fallback: 4096-col strips through 8 MB of ws
    const int SW = 4096;
    for (int is = 0; is < 12; ++is) {
      int n0 = is * SW;
      transpose_h<<<dim3(16, 64, 1), 256, 0, stream>>>(
          Wout + n0, stripH, VOCAB, DMODEL, SW);
      gemm1p<false><<<dim3(16, 16), 512, 0, stream>>>(
          xh, stripH, bout + n0, outf + n0,
          1024, 1024, VOCAB, SW, partials, is * 16);
    }
    int n0 = 12 * SW;                       // 49152
    int ncols = VOCAB - n0;                 // 1105
    int nt64 = (ncols + 63) / 64;           // 18
    int nb256 = (ncols + 255) / 256;        // 5
    transpose_h<<<dim3(16, nt64, 1), 256, 0, stream>>>(
        Wout + n0, stripH, VOCAB, DMODEL, ncols);
    gemm1p<true><<<dim3(16, nb256), 512, 0, stream>>>(
        xh, stripH, bout + n0, outf + n0,
        1024, 1024, VOCAB, ncols, partials, 12 * 16);
  }
  const int ncb = (VOCAB + 255) / 256;      // 197
  scale_softmax<<<S_LEN, 256, 0, stream>>>(outf, partials, ncb);
}

// Round 14
// 3196.964 us; speedup vs baseline: 2.2894x; 2.2894x over previous
//
#include <hip/hip_runtime.h>
#include <math.h>

#define S_LEN  4096
#define DMODEL 1024
#define NHEAD  16
#define DHEAD  64
#define DFF    4096
#define NLAYER 4
#define VOCAB  50257
#define NCBP   400   // partials row stride (col-blocks of 256, padded)

typedef unsigned short ushort_t;
typedef __attribute__((ext_vector_type(8))) __bf16 bf16x8;
typedef __attribute__((ext_vector_type(4))) float f32x4;

static __device__ __forceinline__ ushort_t f2bf(float f) {
  union { float f; unsigned u; } x; x.f = f;
  unsigned r = x.u + 0x7fffu + ((x.u >> 16) & 1u);
  return (ushort_t)(r >> 16);
}
static __device__ __forceinline__ float bf2f(ushort_t h) {
  union { unsigned u; float f; } x; x.u = ((unsigned)h) << 16;
  return x.f;
}
// 2^x via v_exp_f32 (avoid __exp2f: collides with glibc math.h macros)
static __device__ __forceinline__ float exp2fast(float x) {
  return __builtin_amdgcn_exp2f(x);
}

#define GLOAD_LDS16(gp, lp) \
  __builtin_amdgcn_global_load_lds((const __attribute__((address_space(1))) void*)(gp), \
                                   (__attribute__((address_space(3))) void*)(lp), 16, 0, 0)

// q pre-scale: 1/sqrt(64) * log2(e)  (softmax runs in exp2 domain)
#define QSCALE 0.18033688011112042f

// ---------------------------------------------------------------------------
// embedding + sinusoidal positional encoding, fused bf16 split (hi only)
// ---------------------------------------------------------------------------
__global__ __launch_bounds__(256) void embed_kernel(
    const int* __restrict__ tokens, const float* __restrict__ emb,
    float* __restrict__ x, ushort_t* __restrict__ xh)
{
  int s = blockIdx.x;
  int tok = tokens[s];
  int d0 = threadIdx.x * 4;
  const double lf = 0.01798894603901598653; // log(10000)/512
  float4 ev = *(const float4*)(emb + (size_t)tok * DMODEL + d0);
  float o[4]; float evr[4] = {ev.x, ev.y, ev.z, ev.w};
  #pragma unroll
  for (int j = 0; j < 4; ++j) {
    int d = d0 + j;
    int i = (d < 512) ? d : d - 512;
    double ang = (double)s * exp(-lf * (double)i);
    float pe = (d < 512) ? (float)sin(ang) : (float)cos(ang);
    o[j] = evr[j] + pe;
  }
  *(float4*)(x + (size_t)s * DMODEL + d0) = make_float4(o[0], o[1], o[2], o[3]);
  ushort_t hv[4];
  #pragma unroll
  for (int j = 0; j < 4; ++j) hv[j] = f2bf(o[j]);
  *(ushort4*)(xh + (size_t)s * DMODEL + d0) = make_ushort4(hv[0], hv[1], hv[2], hv[3]);
}

// ---------------------------------------------------------------------------
// transpose + split: in f32 [K][N] (row stride in_rstride) -> out bf16 hi/lo
// [N][Kout] K-contiguous. Two-level z batching: z1 = z % zdiv, z2 = z / zdiv.
// ---------------------------------------------------------------------------
__global__ __launch_bounds__(256)
void transpose_split(const float* __restrict__ in, ushort_t* __restrict__ oh,
                     ushort_t* __restrict__ ol,
                     long in_zstr, long out_zoff, long in_z2str, long out_z2off,
                     int zdiv, int in_rstride, int Kout, int Nvalid)
{
  __shared__ float tile[64][65];
  int z1 = blockIdx.z % zdiv, z2 = blockIdx.z / zdiv;
  long ioff = (long)z1 * in_zstr + (long)z2 * in_z2str;
  long ooff = (long)z1 * out_zoff + (long)z2 * out_z2off;
  const float* inz = in + ioff;
  ushort_t* ohz = oh + ooff;
  ushort_t* olz = ol + ooff;
  int k0 = blockIdx.x * 64, n0 = blockIdx.y * 64;
  int t = threadIdx.x;
  #pragma unroll
  for (int i = 0; i < 4; ++i) {
    int idx = t + i * 256;            // 0..1023
    int kk = idx >> 4, c4 = idx & 15;
    #pragma unroll
    for (int j = 0; j < 4; ++j) {
      int n = n0 + c4 * 4 + j;
      float v = (n < Nvalid) ? inz[(long)(k0 + kk) * in_rstride + n] : 0.f;
      tile[c4 * 4 + j][kk] = v;       // transposed into LDS
    }
  }
  __syncthreads();
  #pragma unroll
  for (int i = 0; i < 4; ++i) {
    int idx = t + i * 256;
    int nn = idx >> 4, k4 = idx & 15;
    ushort_t hv[4], lv[4];
    #pragma unroll
    for (int j = 0; j < 4; ++j) {
      float v = tile[nn][k4 * 4 + j];
      hv[j] = f2bf(v);
      lv[j] = f2bf(v - bf2f(hv[j]));
    }
    long ob = (long)(n0 + nn) * Kout + k0 + k4 * 4;
    *(ushort4*)(ohz + ob) = make_ushort4(hv[0], hv[1], hv[2], hv[3]);
    *(ushort4*)(olz + ob) = make_ushort4(lv[0], lv[1], lv[2], lv[3]);
  }
}

// hi-only variant (for the 1-product logits GEMM)
__global__ __launch_bounds__(256)
void transpose_h(const float* __restrict__ in, ushort_t* __restrict__ oh,
                 int in_rstride, int Kout, int Nvalid)
{
  __shared__ float tile[64][65];
  int k0 = blockIdx.x * 64, n0 = blockIdx.y * 64;
  int t = threadIdx.x;
  #pragma unroll
  for (int i = 0; i < 4; ++i) {
    int idx = t + i * 256;
    int kk = idx >> 4, c4 = idx & 15;
    #pragma unroll
    for (int j = 0; j < 4; ++j) {
      int n = n0 + c4 * 4 + j;
      float v = (n < Nvalid) ? in[(long)(k0 + kk) * in_rstride + n] : 0.f;
      tile[c4 * 4 + j][kk] = v;
    }
  }
  __syncthreads();
  #pragma unroll
  for (int i = 0; i < 4; ++i) {
    int idx = t + i * 256;
    int nn = idx >> 4, k4 = idx & 15;
    ushort_t hv[4];
    #pragma unroll
    for (int j = 0; j < 4; ++j) hv[j] = f2bf(tile[nn][k4 * 4 + j]);
    long ob = (long)(n0 + nn) * Kout + k0 + k4 * 4;
    *(ushort4*)(oh + ob) = make_ushort4(hv[0], hv[1], hv[2], hv[3]);
  }
}

// ---------------------------------------------------------------------------
// concat 3 bias vectors of length n into [3n], batched over layers (y)
// ---------------------------------------------------------------------------
__global__ __launch_bounds__(256)
void concat3_kernel(const float* __restrict__ a, const float* __restrict__ b,
                    const float* __restrict__ c, float* __restrict__ o,
                    int n, long lstrA, long lstrO)
{
  int i = blockIdx.x * 256 + threadIdx.x;
  long l = blockIdx.y;
  if (i < n) {
    o[l * lstrO + i]         = a[l * lstrA + i];
    o[l * lstrO + n + i]     = b[l * lstrA + i];
    o[l * lstrO + 2 * n + i] = c[l * lstrA + i];
  }
}

// ---------------------------------------------------------------------------
// 256x256-tile 8-wave GEMM, counted-vmcnt phase pipeline, 2-product split:
// C = Ah @ (Bh + Bl)^T. Streams Ah|Bh|Bl, double-buffered (96 KB LDS).
// EPI: 0 = raw f32 partial (split-K via blockIdx.z), 1 = bf16 hi C (+bias,
// RELU), 2 = QKV routing (q scaled hi/lo, k hi, v -> transposed [H][64][S]).
// ---------------------------------------------------------------------------
template<int EPI, bool RELU>
__global__ __launch_bounds__(512, 2)
void gemm8p(const ushort_t* __restrict__ Ah,
            const ushort_t* __restrict__ Bh, const ushort_t* __restrict__ Bl,
            const float* __restrict__ bias, float* __restrict__ C,
            ushort_t* __restrict__ O0, ushort_t* __restrict__ O1,
            ushort_t* __restrict__ O2, ushort_t* __restrict__ O4,
            int K, int ldk, long ldc, long czStride)
{
  constexpr int BUFSTR = 3 * 8192;              // Ah | Bh | Bl
  constexpr int OBH = 8192, OBL = 16384;
  __shared__ ushort_t lds[2 * BUFSTR];          // 96 KB

  const int t = threadIdx.x;
  const int l = t & 63;
  const int w = t >> 6;            // 0..7
  const int wr = w >> 2;           // 0..1  (row half)
  const int wc = w & 3;            // 0..3  (col quarter)
  const int lrow = l & 15;
  const int lk = (l >> 4) * 8;
  const int l8 = l * 8;
  const long m0 = (long)blockIdx.x * 256;
  const long n0 = (long)blockIdx.y * 256;
  const long kz = (long)blockIdx.z * K;

  const ushort_t *agp[2], *bgp[2], *blgp[2];
  int dst[2];
  #pragma unroll
  for (int i = 0; i < 2; ++i) {
    int s = i * 8 + w;                       // subtile 0..15
    dst[i] = s * 512 + l8;
    agp[i]  = Ah + (m0 + s * 16 + lrow) * (long)ldk + kz + lk;
    bgp[i]  = Bh + (n0 + s * 16 + lrow) * (long)ldk + kz + lk;
    blgp[i] = Bl + (n0 + s * 16 + lrow) * (long)ldk + kz + lk;
  }

  f32x4 acc[8][4];
  #pragma unroll
  for (int m = 0; m < 8; ++m)
    #pragma unroll
    for (int n = 0; n < 4; ++n) acc[m][n] = (f32x4)0.f;

  // prologue: stage tile 0, canonical per-tile order
  GLOAD_LDS16(agp[0],  &lds[dst[0]]);
  GLOAD_LDS16(agp[1],  &lds[dst[1]]);
  GLOAD_LDS16(bgp[0],  &lds[OBH + dst[0]]);
  GLOAD_LDS16(bgp[1],  &lds[OBH + dst[1]]);
  GLOAD_LDS16(blgp[0], &lds[OBL + dst[0]]);
  GLOAD_LDS16(blgp[1], &lds[OBL + dst[1]]);

  const int nk = K >> 5;
  int cur = 0;
  for (int kt = 0; kt < nk; ++kt) {
    const int knx = (kt + 1 < nk) ? (kt + 1) * 32 : 0;  // last iter: harmless reload
    ushort_t* cb = &lds[cur * BUFSTR];
    ushort_t* nb = &lds[(cur ^ 1) * BUFSTR];
    bf16x8 af[8], bhf[4], blf[4];

    // ---------- P0: needs Ah,Bh of tile kt ----------
    asm volatile("s_waitcnt vmcnt(2)" ::: "memory");
    __builtin_amdgcn_sched_barrier(0);
    __builtin_amdgcn_s_barrier();
    __builtin_amdgcn_sched_barrier(0);
    #pragma unroll
    for (int m = 0; m < 8; ++m)
      af[m] = *(const bf16x8*)&cb[(wr * 8 + m) * 512 + l8];
    #pragma unroll
    for (int n = 0; n < 4; ++n)
      bhf[n] = *(const bf16x8*)&cb[OBH + (wc * 4 + n) * 512 + l8];
    GLOAD_LDS16(agp[0] + knx, &nb[dst[0]]);
    GLOAD_LDS16(agp[1] + knx, &nb[dst[1]]);
    GLOAD_LDS16(bgp[0] + knx, &nb[OBH + dst[0]]);
    __builtin_amdgcn_s_setprio(1);
    #pragma unroll
    for (int m = 0; m < 8; ++m)
      #pragma unroll
      for (int n = 0; n < 4; ++n)
        acc[m][n] = __builtin_amdgcn_mfma_f32_16x16x32_bf16(af[m], bhf[n], acc[m][n], 0, 0, 0);
    __builtin_amdgcn_s_setprio(0);
    __builtin_amdgcn_sched_barrier(0);

    // ---------- P1: needs Bl of tile kt ----------
    asm volatile("s_waitcnt vmcnt(3)" ::: "memory");
    __builtin_amdgcn_sched_barrier(0);
    __builtin_amdgcn_s_barrier();
    __builtin_amdgcn_sched_barrier(0);
    #pragma unroll
    for (int n = 0; n < 4; ++n)
      blf[n] = *(const bf16x8*)&cb[OBL + (wc * 4 + n) * 512 + l8];
    GLOAD_LDS16(bgp[1] + knx,  &nb[OBH + dst[1]]);
    GLOAD_LDS16(blgp[0] + knx, &nb[OBL + dst[0]]);
    GLOAD_LDS16(blgp[1] + knx, &nb[OBL + dst[1]]);
    __builtin_amdgcn_s_setprio(1);
    #pragma unroll
    for (int m = 0; m < 8; ++m)
      #pragma unroll
      for (int n = 0; n < 4; ++n)
        acc[m][n] = __builtin_amdgcn_mfma_f32_16x16x32_bf16(af[m], blf[n], acc[m][n], 0, 0, 0);
    __builtin_amdgcn_s_setprio(0);
    __builtin_amdgcn_sched_barrier(0);
    cur ^= 1;
  }
  asm volatile("s_waitcnt vmcnt(0)" ::: "memory");

  // ---------------- epilogue (row-major store order for line combining) ----
  if constexpr (EPI == 2) {
    #pragma unroll
    for (int n = 0; n < 4; ++n) {
      long col = n0 + wc * 64 + n * 16 + lrow;
      float bv = bias[col];
      #pragma unroll
      for (int m = 0; m < 8; ++m) {
        #pragma unroll
        for (int r = 0; r < 4; ++r) {
          long row = m0 + wr * 128 + m * 16 + (l >> 4) * 4 + r;
          float v = acc[m][n][r] + bv;
          int c = (int)col;
          if (c < 1024) {
            int hh = c >> 6, e = c & 63;
            float qv = v * QSCALE;            // fold 1/sqrt(DH)*log2e
            ushort_t hi = f2bf(qv);
            size_t a = ((size_t)hh * S_LEN + row) * 64 + e;
            O0[a] = hi; O1[a] = f2bf(qv - bf2f(hi));
          } else if (c < 2048) {
            int cc = c - 1024;
            int hh = cc >> 6, e = cc & 63;
            size_t a = ((size_t)hh * S_LEN + row) * 64 + e;
            O2[a] = f2bf(v);
          } else {
            // V: write transposed directly -> vt[h][e][row]
            int cc = c - 2048;
            int hh = cc >> 6, e = cc & 63;
            size_t a = ((size_t)hh * DHEAD + e) * S_LEN + row;
            O4[a] = f2bf(v);
          }
        }
      }
    }
  } else if constexpr (EPI == 1) {
    long col4[4]; float bv4[4];
    #pragma unroll
    for (int n = 0; n < 4; ++n) {
      col4[n] = n0 + wc * 64 + n * 16 + lrow;
      bv4[n] = bias[col4[n]];
    }
    #pragma unroll
    for (int m = 0; m < 8; ++m) {
      #pragma unroll
      for (int r = 0; r < 4; ++r) {
        long row = m0 + wr * 128 + m * 16 + (l >> 4) * 4 + r;
        ushort_t* crow = O0 + row * ldc;
        #pragma unroll
        for (int n = 0; n < 4; ++n) {
          float v = acc[m][n][r] + bv4[n];
          if (RELU) v = fmaxf(v, 0.f);
          crow[col4[n]] = f2bf(v);
        }
      }
    }
  } else {  // EPI == 0: raw f32 partial (split-K), no bias
    float* Cz = C + (long)blockIdx.z * czStride;
    long col4[4];
    #pragma unroll
    for (int n = 0; n < 4; ++n) col4[n] = n0 + wc * 64 + n * 16 + lrow;
    #pragma unroll
    for (int m = 0; m < 8; ++m) {
      #pragma unroll
      for (int r = 0; r < 4; ++r) {
        long row = m0 + wr * 128 + m * 16 + (l >> 4) * 4 + r;
        float* crow = Cz + row * ldc;
        #pragma unroll
        for (int n = 0; n < 4; ++n) crow[col4[n]] = acc[m][n][r];
      }
    }
  }
}

// ---------------------------------------------------------------------------
// 1-product 256x256 GEMM (logits): C = exp(Ah@Bh^T + bias), per-row partials.
// 3-buffer rotation, 2-tile-deep prefetch, vmcnt(4) counted wait, ONE barrier
// per K-step; prefetch issued between ds_read and the 32-MFMA cluster.
// ---------------------------------------------------------------------------
template<bool BOUND>
__global__ __launch_bounds__(512, 2)
void gemm1p(const ushort_t* __restrict__ Ah, const ushort_t* __restrict__ Bh,
            const float* __restrict__ bias, float* __restrict__ C,
            int K, int ldk, long ldc, int Nlimit,
            float* __restrict__ Ppart, int cbbase)
{
  constexpr int OB = 8192;
  constexpr int BUFSTR = 16384;       // shorts per buffer (A 16KB | B 16KB)
  __shared__ ushort_t lds[3 * BUFSTR];  // 96 KB, 3-buffer rotation
  __shared__ float psum[1024];

  const int t = threadIdx.x;
  const int l = t & 63;
  const int w = t >> 6;
  const int wr = w >> 2;
  const int wc = w & 3;
  const int lrow = l & 15;
  const int lk = (l >> 4) * 8;
  const int l8 = l * 8;
  const long m0 = (long)blockIdx.x * 256;
  const long n0 = (long)blockIdx.y * 256;

  const ushort_t *agp[2], *bgp[2];
  int dst[2];
  #pragma unroll
  for (int i = 0; i < 2; ++i) {
    int s = i * 8 + w;
    dst[i] = s * 512 + l8;
    agp[i] = Ah + (m0 + s * 16 + lrow) * (long)ldk + lk;
    bgp[i] = Bh + (n0 + s * 16 + lrow) * (long)ldk + lk;
  }

  f32x4 acc[8][4];
  #pragma unroll
  for (int m = 0; m < 8; ++m)
    #pragma unroll
    for (int n = 0; n < 4; ++n) acc[m][n] = (f32x4)0.f;

  // prologue: tile 0 -> buf0, tile 1 -> buf1 (8 loads outstanding)
  GLOAD_LDS16(agp[0], &lds[dst[0]]);
  GLOAD_LDS16(agp[1], &lds[dst[1]]);
  GLOAD_LDS16(bgp[0], &lds[OB + dst[0]]);
  GLOAD_LDS16(bgp[1], &lds[OB + dst[1]]);
  GLOAD_LDS16(agp[0] + 32, &lds[BUFSTR + dst[0]]);
  GLOAD_LDS16(agp[1] + 32, &lds[BUFSTR + dst[1]]);
  GLOAD_LDS16(bgp[0] + 32, &lds[BUFSTR + OB + dst[0]]);
  GLOAD_LDS16(bgp[1] + 32, &lds[BUFSTR + OB + dst[1]]);

  const int nk = K >> 5;
  int cur = 0;
  for (int kt = 0; kt < nk; ++kt) {
    ushort_t* cb = &lds[cur * BUFSTR];
    int nxt = cur + 2; if (nxt >= 3) nxt -= 3;
    ushort_t* nb = &lds[nxt * BUFSTR];
    bf16x8 af[8], bhf[4];

    asm volatile("s_waitcnt vmcnt(4)" ::: "memory");   // tile kt landed
    __builtin_amdgcn_sched_barrier(0);
    __builtin_amdgcn_s_barrier();
    __builtin_amdgcn_sched_barrier(0);
    #pragma unroll
    for (int m = 0; m < 8; ++m)
      af[m] = *(const bf16x8*)&cb[(wr * 8 + m) * 512 + l8];
    #pragma unroll
    for (int n = 0; n < 4; ++n)
      bhf[n] = *(const bf16x8*)&cb[OB + (wc * 4 + n) * 512 + l8];
    const int knx2 = (kt + 2 < nk) ? (kt + 2) * 32 : 0;  // tail: harmless refill
    GLOAD_LDS16(agp[0] + knx2, &nb[dst[0]]);
    GLOAD_LDS16(agp[1] + knx2, &nb[dst[1]]);
    GLOAD_LDS16(bgp[0] + knx2, &nb[OB + dst[0]]);
    GLOAD_LDS16(bgp[1] + knx2, &nb[OB + dst[1]]);
    __builtin_amdgcn_s_setprio(1);
    #pragma unroll
    for (int m = 0; m < 8; ++m)
      #pragma unroll
      for (int n = 0; n < 4; ++n)
        acc[m][n] = __builtin_amdgcn_mfma_f32_16x16x32_bf16(af[m], bhf[n], acc[m][n], 0, 0, 0);
    __builtin_amdgcn_s_setprio(0);
    __builtin_amdgcn_sched_barrier(0);
    cur = (cur == 2) ? 0 : cur + 1;
  }
  asm volatile("s_waitcnt vmcnt(0)" ::: "memory");

  // epilogue: exp(logit), row-major store order + deterministic partial sums
  float smr[8][4];
  #pragma unroll
  for (int m = 0; m < 8; ++m)
    #pragma unroll
    for (int r = 0; r < 4; ++r) smr[m][r] = 0.f;
  long col4[4]; float bv4[4]; bool cok4[4];
  #pragma unroll
  for (int n = 0; n < 4; ++n) {
    col4[n] = n0 + wc * 64 + n * 16 + lrow;
    cok4[n] = (!BOUND) || (col4[n] < (long)Nlimit);
    bv4[n] = cok4[n] ? bias[col4[n]] : 0.f;
  }
  #pragma unroll
  for (int m = 0; m < 8; ++m) {
    #pragma unroll
    for (int r = 0; r < 4; ++r) {
      long row = m0 + wr * 128 + m * 16 + (l >> 4) * 4 + r;
      float* crow = C + row * ldc;
      #pragma unroll
      for (int n = 0; n < 4; ++n) {
        float e = cok4[n] ? __expf(acc[m][n][r] + bv4[n]) : 0.f;
        if (cok4[n]) crow[col4[n]] = e;
        smr[m][r] += e;
      }
    }
  }
  #pragma unroll
  for (int m = 0; m < 8; ++m) {
    #pragma unroll
    for (int r = 0; r < 4; ++r) {
      float s = smr[m][r];
      s += __shfl_xor(s, 1);
      s += __shfl_xor(s, 2);
      s += __shfl_xor(s, 4);
      s += __shfl_xor(s, 8);
      if (lrow == 0)
        psum[wc * 256 + wr * 128 + m * 16 + (l >> 4) * 4 + r] = s;
    }
  }
  __syncthreads();
  if (t < 256) {
    float s = psum[t] + psum[256 + t] + psum[512 + t] + psum[768 + t];
    Ppart[(m0 + t) * NCBP + cbbase + blockIdx.y] = s;
  }
}

// ---------------------------------------------------------------------------
// MFMA flash attention v3. qh/ql: [H][S][64] bf16 (pre-scaled by QSCALE),
// kh: [H][S][64] bf16, vt: [H][64][S] bf16. y: [S][1024] f32.
// 2-product QK^T; exp2-domain softmax; defer-rescale vote; K/V double-buffer
// with next-tile loads issued a full compute-phase early (1 barrier/tile).
// ---------------------------------------------------------------------------
__global__ __launch_bounds__(256)
void attn_mfma(const ushort_t* __restrict__ qh, const ushort_t* __restrict__ ql,
               const ushort_t* __restrict__ kh, const ushort_t* __restrict__ vt,
               float* __restrict__ y)
{
  __shared__ ushort_t lds[24576];  // buf0 K|V [8192], buf1 K|V [8192], P [4][2048]

  const int t = threadIdx.x, l = t & 63, w = t >> 6;
  const int lrow = l & 15, lhi = l >> 4;
  const int h = blockIdx.y;
  const int bw = blockIdx.x * 128 + w * 32;
  const size_t hS = (size_t)h * S_LEN * DHEAD;
  const size_t hV = (size_t)h * DHEAD * S_LEN;
  const int pb = 16384 + w * 2048;

  bf16x8 qhf[2][2], qlf[2][2];
  #pragma unroll
  for (int m = 0; m < 2; ++m)
    #pragma unroll
    for (int ks = 0; ks < 2; ++ks) {
      size_t a = hS + (size_t)(bw + m * 16 + lrow) * 64 + ks * 32 + lhi * 8;
      qhf[m][ks] = *(const bf16x8*)(qh + a);
      qlf[m][ks] = *(const bf16x8*)(ql + a);
    }

  f32x4 acc[2][4];
  #pragma unroll
  for (int m = 0; m < 2; ++m)
    #pragma unroll
    for (int n = 0; n < 4; ++n) acc[m][n] = (f32x4)0.f;
  float mrow[8], lsum[8];
  #pragma unroll
  for (int i = 0; i < 8; ++i) { mrow[i] = -1e30f; lsum[i] = 0.f; }

  // prologue: stage tile 0 into buf 0
  #pragma unroll
  for (int i = 0; i < 2; ++i) {
    int s = i * 4 + w;
    size_t krow = (size_t)((s >> 1) * 16 + lrow);
    int koff = (s & 1) * 32 + lhi * 8;
    GLOAD_LDS16(kh + hS + krow * 64 + koff, &lds[s * 512 + l * 8]);
    int toff = (s & 1) * 32 + lhi * 8;
    GLOAD_LDS16(vt + hV + krow * S_LEN + toff, &lds[4096 + s * 512 + l * 8]);
  }

  int cur = 0;
  for (int kt = 0; kt < S_LEN; kt += 64) {
    asm volatile("s_waitcnt vmcnt(0)" ::: "memory");
    __builtin_amdgcn_sched_barrier(0);
    __builtin_amdgcn_s_barrier();
    __builtin_amdgcn_sched_barrier(0);
    ushort_t* cb = &lds[cur * 8192];
    // issue next-tile loads into the other buffer (hidden under compute)
    if (kt + 64 < S_LEN) {
      ushort_t* nb = &lds[(cur ^ 1) * 8192];
      int kn = kt + 64;
      #pragma unroll
      for (int i = 0; i < 2; ++i) {
        int s = i * 4 + w;
        size_t krow = (size_t)(kn + (s >> 1) * 16 + lrow);
        int koff = (s & 1) * 32 + lhi * 8;
        GLOAD_LDS16(kh + hS + krow * 64 + koff, &nb[s * 512 + l * 8]);
        size_t erow = (size_t)((s >> 1) * 16 + lrow);
        int toff = kn + (s & 1) * 32 + lhi * 8;
        GLOAD_LDS16(vt + hV + erow * S_LEN + toff, &nb[4096 + s * 512 + l * 8]);
      }
    }

    // scores (exp2 domain), 2-product: (qh + ql) * kh
    f32x4 sacc[2][4];
    #pragma unroll
    for (int m = 0; m < 2; ++m)
      #pragma unroll
      for (int n = 0; n < 4; ++n) sacc[m][n] = (f32x4)0.f;
    #pragma unroll
    for (int ks = 0; ks < 2; ++ks) {
      bf16x8 bh_[4];
      #pragma unroll
      for (int n = 0; n < 4; ++n)
        bh_[n] = *(const bf16x8*)&cb[(n * 2 + ks) * 512 + l * 8];
      #pragma unroll
      for (int m = 0; m < 2; ++m)
        #pragma unroll
        for (int n = 0; n < 4; ++n) {
          sacc[m][n] = __builtin_amdgcn_mfma_f32_16x16x32_bf16(qhf[m][ks], bh_[n], sacc[m][n], 0, 0, 0);
          sacc[m][n] = __builtin_amdgcn_mfma_f32_16x16x32_bf16(qlf[m][ks], bh_[n], sacc[m][n], 0, 0, 0);
        }
    }

    // tile maxes + wave vote (defer rescale when no row's max grew)
    float tmv[2][4];
    bool up = false;
    #pragma unroll
    for (int m = 0; m < 2; ++m) {
      #pragma unroll
      for (int r = 0; r < 4; ++r) {
        float tm = fmaxf(fmaxf(sacc[m][0][r], sacc[m][1][r]),
                         fmaxf(sacc[m][2][r], sacc[m][3][r]));
        tm = fmaxf(tm, __shfl_xor(tm, 1));
        tm = fmaxf(tm, __shfl_xor(tm, 2));
        tm = fmaxf(tm, __shfl_xor(tm, 4));
        tm = fmaxf(tm, __shfl_xor(tm, 8));
        tmv[m][r] = tm;
        up = up || (tm > mrow[m * 4 + r]);
      }
    }
    if (__ballot(up) != 0ULL) {
      #pragma unroll
      for (int m = 0; m < 2; ++m) {
        #pragma unroll
        for (int r = 0; r < 4; ++r) {
          const int idx = m * 4 + r;
          float mn = fmaxf(mrow[idx], tmv[m][r]);
          float al = exp2fast(mrow[idx] - mn);
          mrow[idx] = mn;
          lsum[idx] *= al;
          #pragma unroll
          for (int n = 0; n < 4; ++n) acc[m][n][r] *= al;
        }
      }
    }
    #pragma unroll
    for (int m = 0; m < 2; ++m) {
      #pragma unroll
      for (int r = 0; r < 4; ++r) {
        const int idx = m * 4 + r;
        float rs = 0.f;
        #pragma unroll
        for (int n = 0; n < 4; ++n) {
          float p = exp2fast(sacc[m][n][r] - mrow[idx]);
          rs += p;
          int pa = pb + ((m * 2 + (n >> 1)) << 9) + (((n & 1) * 2 + (lrow >> 3)) << 7)
                   + ((lhi * 4 + r) << 3) + (l & 7);
          pa ^= (lrow >> 3) << 3;
          lds[pa] = f2bf(p);
        }
        rs += __shfl_xor(rs, 1);
        rs += __shfl_xor(rs, 2);
        rs += __shfl_xor(rs, 4);
        rs += __shfl_xor(rs, 8);
        lsum[idx] += rs;
      }
    }

    // O += P V
    #pragma unroll
    for (int ks = 0; ks < 2; ++ks) {
      bf16x8 pa_[2];
      #pragma unroll
      for (int m = 0; m < 2; ++m) {
        int ra = pb + ((m * 2 + ks) << 9) + (l << 3);
        ra ^= ((l >> 4) & 1) << 3;
        pa_[m] = *(const bf16x8*)&lds[ra];
      }
      #pragma unroll
      for (int n = 0; n < 4; ++n) {
        bf16x8 vf = *(const bf16x8*)&cb[4096 + (n * 2 + ks) * 512 + l * 8];
        #pragma unroll
        for (int m = 0; m < 2; ++m)
          acc[m][n] = __builtin_amdgcn_mfma_f32_16x16x32_bf16(pa_[m], vf, acc[m][n], 0, 0, 0);
      }
    }
    cur ^= 1;
  }

  #pragma unroll
  for (int m = 0; m < 2; ++m) {
    #pragma unroll
    for (int r = 0; r < 4; ++r) {
      float inv = 1.0f / lsum[m * 4 + r];
      int row = bw + m * 16 + lhi * 4 + r;
      #pragma unroll
      for (int n = 0; n < 4; ++n)
        y[(size_t)row * DMODEL + h * 64 + n * 16 + lrow] = acc[m][n][r] * inv;
    }
  }
}

// ---------------------------------------------------------------------------
__device__ __forceinline__ float block_sum256(float v, float* sm)
{
  #pragma unroll
  for (int off = 32; off >= 1; off >>= 1) v += __shfl_xor(v, off);
  int w = threadIdx.x >> 6;
  if ((threadIdx.x & 63) == 0) sm[w] = v;
  __syncthreads();
  v = sm[0] + sm[1] + sm[2] + sm[3];
  __syncthreads();
  return v;
}

// x = layernorm(x + y) * g + b, fused bf16 (hi only) split of the result
__global__ __launch_bounds__(256)
void resid_ln_kernel(float* __restrict__ x, const float* __restrict__ y,
                     const float* __restrict__ g, const float* __restrict__ b,
                     ushort_t* __restrict__ xh)
{
  __shared__ float sm[4];
  int row = blockIdx.x, t = threadIdx.x;
  float4 xv = *(const float4*)(x + (size_t)row * DMODEL + t * 4);
  float4 yv = *(const float4*)(y + (size_t)row * DMODEL + t * 4);
  float a0 = xv.x + yv.x, a1 = xv.y + yv.y, a2 = xv.z + yv.z, a3 = xv.w + yv.w;
  float s = block_sum256(a0 + a1 + a2 + a3, sm);
  float mean = s * (1.0f / DMODEL);
  float d0 = a0 - mean, d1 = a1 - mean, d2 = a2 - mean, d3 = a3 - mean;
  float vs = block_sum256(d0*d0 + d1*d1 + d2*d2 + d3*d3, sm);
  float inv = rsqrtf(vs * (1.0f / DMODEL) + 1e-5f);
  float4 gv = *(const float4*)(g + t * 4);
  float4 bv = *(const float4*)(b + t * 4);
  float o[4];
  o[0] = d0 * inv * gv.x + bv.x;
  o[1] = d1 * inv * gv.y + bv.y;
  o[2] = d2 * inv * gv.z + bv.z;
  o[3] = d3 * inv * gv.w + bv.w;
  *(float4*)(x + (size_t)row * DMODEL + t * 4) = make_float4(o[0], o[1], o[2], o[3]);
  ushort_t hv[4];
  #pragma unroll
  for (int j = 0; j < 4; ++j) hv[j] = f2bf(o[j]);
  *(ushort4*)(xh + (size_t)row * DMODEL + t * 4) = make_ushort4(hv[0], hv[1], hv[2], hv[3]);
}

// ---------------------------------------------------------------------------
// x = layernorm(x + sum_{z<4} parts[z] + bias) * g + b, fused bf16 hi split.
// ---------------------------------------------------------------------------
__global__ __launch_bounds__(256)
void resid_ln_red(float* __restrict__ x, const float* __restrict__ parts,
                  long pstride, const float* __restrict__ bias,
                  const float* __restrict__ g, const float* __restrict__ b,
                  ushort_t* __restrict__ xh)
{
  __shared__ float sm[4];
  int row = blockIdx.x, t = threadIdx.x;
  size_t base = (size_t)row * DMODEL + t * 4;
  float4 xv = *(const float4*)(x + base);
  float4 bb = *(const float4*)(bias + t * 4);
  float a0 = xv.x + bb.x, a1 = xv.y + bb.y, a2 = xv.z + bb.z, a3 = xv.w + bb.w;
  #pragma unroll
  for (int z = 0; z < 4; ++z) {
    float4 pv = *(const float4*)(parts + (size_t)z * pstride + base);
    a0 += pv.x; a1 += pv.y; a2 += pv.z; a3 += pv.w;
  }
  float s = block_sum256(a0 + a1 + a2 + a3, sm);
  float mean = s * (1.0f / DMODEL);
  float d0 = a0 - mean, d1 = a1 - mean, d2 = a2 - mean, d3 = a3 - mean;
  float vs = block_sum256(d0*d0 + d1*d1 + d2*d2 + d3*d3, sm);
  float inv = rsqrtf(vs * (1.0f / DMODEL) + 1e-5f);
  float4 gv = *(const float4*)(g + t * 4);
  float4 bv = *(const float4*)(b + t * 4);
  float o[4];
  o[0] = d0 * inv * gv.x + bv.x;
  o[1] = d1 * inv * gv.y + bv.y;
  o[2] = d2 * inv * gv.z + bv.z;
  o[3] = d3 * inv * gv.w + bv.w;
  *(float4*)(x + base) = make_float4(o[0], o[1], o[2], o[3]);
  ushort_t hv[4];
  #pragma unroll
  for (int j = 0; j < 4; ++j) hv[j] = f2bf(o[j]);
  *(ushort4*)(xh + base) = make_ushort4(hv[0], hv[1], hv[2], hv[3]);
}

// ---------------------------------------------------------------------------
// final scale: out[row] *= 1/sum(row); sum from deterministic partials
// ---------------------------------------------------------------------------
__global__ __launch_bounds__(256)
void scale_softmax(float* __restrict__ out, const float* __restrict__ partials,
                   int ncb)
{
  __shared__ float sm[4];
  int row = blockIdx.x, t = threadIdx.x;
  float s = 0.f;
  for (int cb = t; cb < ncb; cb += 256) s += partials[(size_t)row * NCBP + cb];
  s = block_sum256(s, sm);
  float inv = 1.0f / s;
  float* p = out + (size_t)row * VOCAB;
  int head = (int)((((uintptr_t)16 - ((uintptr_t)p & 15)) & 15) >> 2);
  if (t < head) p[t] *= inv;
  int nvec = (VOCAB - head) >> 2;
  float4* pv = (float4*)(p + head);
  for (int i = t; i < nvec; i += 256) {
    float4 v = pv[i];
    v.x *= inv; v.y *= inv; v.z *= inv; v.w *= inv;
    pv[i] = v;
  }
  int done = head + nvec * 4;
  if (t < VOCAB - done) p[done + t] *= inv;
}

// ---------------------------------------------------------------------------
extern "C" void kernel_launch(void* const* d_in, const int* in_sizes, int n_in,
                              void* d_out, int out_size, void* d_ws, size_t ws_size,
                              hipStream_t stream)
{
  const int*   tokens = (const int*)  d_in[0];
  const float* emb    = (const float*)d_in[1];
  const float* Wq     = (const float*)d_in[2];
  const float* bq     = (const float*)d_in[3];
  const float* Wk     = (const float*)d_in[4];
  const float* bk     = (const float*)d_in[5];
  const float* Wv     = (const float*)d_in[6];
  const float* bv     = (const float*)d_in[7];
  const float* ln1g   = (const float*)d_in[8];
  const float* ln1b   = (const float*)d_in[9];
  const float* W1     = (const float*)d_in[10];
  const float* b1     = (const float*)d_in[11];
  const float* W2     = (const float*)d_in[12];
  const float* b2     = (const float*)d_in[13];
  const float* ln2g   = (const float*)d_in[14];
  const float* ln2b   = (const float*)d_in[15];
  const float* Wout   = (const float*)d_in[16];
  const float* bout   = (const float*)d_in[17];

  // workspace: xh 0-8 MB; strip path stripH 8-16; partials 24-30.55;
  // big path (ws >= 137 MB): WoutT at 32 MB (50304x1024 bf16 = 103 MB)
  char* wsb = (char*)d_ws;
  ushort_t* xh     = (ushort_t*)(wsb);
  ushort_t* stripH = (ushort_t*)(wsb + ((size_t)8  << 20));
  float*    partials = (float*)(wsb + ((size_t)24 << 20)); // [4096][NCBP] f32
  ushort_t* woutT  = (ushort_t*)(wsb + ((size_t)32 << 20));
  const bool bigws = ws_size >= ((size_t)137 << 20);

  // scratch in d_out (823 MB; all dead before the logits GEMM writes it)
  char* ob = (char*)d_out;
  float*    x     = (float*)(ob);                          // [S][D] f32 16MB
  float*    yb    = (float*)(ob + ((size_t)16  << 20));    // [S][D] f32 16MB
  ushort_t* qh    = (ushort_t*)(ob + ((size_t)32  << 20)); // [H][S][64] 8MB
  ushort_t* ql    = (ushort_t*)(ob + ((size_t)40  << 20));
  ushort_t* kh    = (ushort_t*)(ob + ((size_t)48  << 20));
  ushort_t* vt    = (ushort_t*)(ob + ((size_t)56  << 20)); // [H][64][S] 8MB
  ushort_t* h1h   = (ushort_t*)(ob + ((size_t)64  << 20)); // [S][DFF] bf16 32MB
  float*    fparts= (float*)(ob + ((size_t)96  << 20));    // [4][S][D] f32 64MB
  ushort_t* wqkvhA= (ushort_t*)(ob + ((size_t)160 << 20)); // [L][3072][1024] 24MB
  ushort_t* wqkvlA= (ushort_t*)(ob + ((size_t)184 << 20));
  ushort_t* w1hA  = (ushort_t*)(ob + ((size_t)208 << 20)); // [L][4096][1024] 32MB
  ushort_t* w1lA  = (ushort_t*)(ob + ((size_t)240 << 20));
  ushort_t* w2hA  = (ushort_t*)(ob + ((size_t)272 << 20)); // [L][1024][4096] 32MB
  ushort_t* w2lA  = (ushort_t*)(ob + ((size_t)304 << 20));
  float*    bqkvA = (float*)(ob + ((size_t)336 << 20));    // [L][3072] f32
  float*    outf  = (float*)d_out;

  const long WQKV_L = 3072L * 1024;   // shorts per layer
  const long WFF_L  = 4096L * 1024;

  embed_kernel<<<S_LEN, 256, 0, stream>>>(tokens, emb, x, xh);

  // ---- hoisted weight prep (activation-independent) ----
  transpose_split<<<dim3(16, 1, 64), 256, 0, stream>>>(
      Wq, wqkvhA, wqkvlA,
      (long)DMODEL * DHEAD, (long)DHEAD * DMODEL,
      (long)NHEAD * DMODEL * DHEAD, WQKV_L,
      16, DHEAD, DMODEL, DHEAD);
  transpose_split<<<dim3(16, 1, 64), 256, 0, stream>>>(
      Wk, wqkvhA + 1024 * 1024, wqkvlA + 1024 * 1024,
      (long)DMODEL * DHEAD, (long)DHEAD * DMODEL,
      (long)NHEAD * DMODEL * DHEAD, WQKV_L,
      16, DHEAD, DMODEL, DHEAD);
  transpose_split<<<dim3(16, 1, 64), 256, 0, stream>>>(
      Wv, wqkvhA + 2048 * 1024, wqkvlA + 2048 * 1024,
      (long)DMODEL * DHEAD, (long)DHEAD * DMODEL,
      (long)NHEAD * DMODEL * DHEAD, WQKV_L,
      16, DHEAD, DMODEL, DHEAD);
  transpose_split<<<dim3(16, 64, 4), 256, 0, stream>>>(
      W1, w1hA, w1lA, 0, 0,
      (long)DMODEL * DFF, WFF_L, 1, DFF, DMODEL, DFF);
  transpose_split<<<dim3(64, 16, 4), 256, 0, stream>>>(
      W2, w2hA, w2lA, 0, 0,
      (long)DFF * DMODEL, WFF_L, 1, DMODEL, DFF, DMODEL);
  concat3_kernel<<<dim3(4, NLAYER), 256, 0, stream>>>(
      bq, bk, bv, bqkvA, 1024, 1024, 3072);

  for (int l = 0; l < NLAYER; ++l) {
    const ushort_t* wqh = wqkvhA + (long)l * WQKV_L;
    const ushort_t* wql = wqkvlA + (long)l * WQKV_L;
    const ushort_t* w1h = w1hA + (long)l * WFF_L;
    const ushort_t* w1l = w1lA + (long)l * WFF_L;
    const ushort_t* w2h = w2hA + (long)l * WFF_L;
    const ushort_t* w2l = w2lA + (long)l * WFF_L;

    // fused QKV projection: 2-prod, grid 16x12; V written transposed
    gemm8p<2, false><<<dim3(16, 12), 512, 0, stream>>>(
        xh, wqh, wql, bqkvA + (long)l * 3072, nullptr,
        qh, ql, kh, vt, 1024, 1024, 0, 0);

    attn_mfma<<<dim3(32, 16), 256, 0, stream>>>(qh, ql, kh, vt, yb);

    resid_ln_kernel<<<S_LEN, 256, 0, stream>>>(x, yb,
        ln1g + (size_t)l * DMODEL, ln1b + (size_t)l * DMODEL, xh);

    // FFN1: 2-prod, grid 16x16, bf16-hi output
    gemm8p<1, true><<<dim3(16, 16), 512, 0, stream>>>(
        xh, w1h, w1l, b1 + (long)l * DFF, nullptr,
        h1h, nullptr, nullptr, nullptr, 1024, 1024, 4096, 0);
    // FFN2: 2-prod split-K x4 (grid 16x4x4), f32 partials
    gemm8p<0, false><<<dim3(16, 4, 4), 512, 0, stream>>>(
        h1h, w2h, w2l, nullptr, fparts,
        nullptr, nullptr, nullptr, nullptr,
        1024, 4096, 1024, (long)S_LEN * DMODEL);
    resid_ln_red<<<S_LEN, 256, 0, stream>>>(x, fparts, (long)S_LEN * DMODEL,
        b2 + (long)l * DMODEL,
        ln2g + (size_t)l * DMODEL, ln2b + (size_t)l * DMODEL, xh);
  }

  if (bigws) {
    // single-shot logits: whole Wout^T (hi) staged in ws, one GEMM
    transpose_h<<<dim3(16, 786, 1), 256, 0, stream>>>(
        Wout, woutT, VOCAB, DMODEL, VOCAB);
    gemm1p<true><<<dim3(16, 197), 512, 0, stream>>>(
        xh, woutT, bout, outf, 1024, 1024, VOCAB, VOCAB, partials, 0);
  } else {
    // fallback: 4096-col strips through 8 MB of ws
    const int SW = 4096;
    for (int is = 0; is < 12; ++is) {
      int n0 = is * SW;
      transpose_h<<<dim3(16, 64, 1), 256, 0, stream>>>(
          Wout + n0, stripH, VOCAB, DMODEL, SW);
      gemm1p<false><<<dim3(16, 16), 512, 0, stream>>>(
          xh, stripH, bout + n0, outf + n0,
          1024, 1024, VOCAB, SW, partials, is * 16);
    }
    int n0 = 12 * SW;                       // 49152
    int ncols = VOCAB - n0;                 // 1105
    int nt64 = (ncols + 63) / 64;           // 18
    int nb256 = (ncols + 255) / 256;        // 5
    transpose_h<<<dim3(16, nt64, 1), 256, 0, stream>>>(
        Wout + n0, stripH, VOCAB, DMODEL, ncols);
    gemm1p<true><<<dim3(16, nb256), 512, 0, stream>>>(
        xh, stripH, bout + n0, outf + n0,
        1024, 1024, VOCAB, ncols, partials, 12 * 16);
  }
  const int ncb = (VOCAB + 255) / 256;      // 197
  scale_softmax<<<S_LEN, 256, 0, stream>>>(outf, partials, ncb);
}